// Round 1
// baseline (1080.612 us; speedup 1.0000x reference)
//
#include <hip/hip_runtime.h>

// ---------------------------------------------------------------------------
// DeformConv stack: 8 layers, N=4, H=W=64.
// dims: L0 (512->256, k=1, pad=0), L1 (256->128, 3x3), L2..L7 (128->128, 3x3)
// Strategy: NHWC activations, per-tap bilinear im2col into LDS, fp32 GEMM.
// ---------------------------------------------------------------------------

// NCHW -> NHWC tile transpose. grid: ((C/32)*2, 64, N), block 256.
__global__ __launch_bounds__(256) void nchw2nhwc(const float* __restrict__ in,
                                                 float* __restrict__ out, int C) {
    const int ctiles = C >> 5;
    const int ct = blockIdx.x % ctiles;
    const int xt = blockIdx.x / ctiles;
    const int y = blockIdx.y, n = blockIdx.z;
    const int c0 = ct * 32, x0 = xt * 32;
    __shared__ float tile[32][33];
    const int tx = threadIdx.x & 31, tr = threadIdx.x >> 5;
#pragma unroll
    for (int r = 0; r < 32; r += 8) {
        const int c = c0 + tr + r;
        tile[tr + r][tx] = in[(((n * C + c) << 6) + y) * 64 + x0 + tx]; // tile[c][x]
    }
    __syncthreads();
#pragma unroll
    for (int r = 0; r < 32; r += 8) {
        const int x = x0 + tr + r;
        out[((((n << 6) + y) * 64) + x) * C + c0 + tx] = tile[tx][tr + r];
    }
}

// NHWC -> NCHW tile transpose. grid: ((C/32)*2, 64, N), block 256.
__global__ __launch_bounds__(256) void nhwc2nchw(const float* __restrict__ in,
                                                 float* __restrict__ out, int C) {
    const int ctiles = C >> 5;
    const int ct = blockIdx.x % ctiles;
    const int xt = blockIdx.x / ctiles;
    const int y = blockIdx.y, n = blockIdx.z;
    const int c0 = ct * 32, x0 = xt * 32;
    __shared__ float tile[32][33];
    const int tx = threadIdx.x & 31, tr = threadIdx.x >> 5;
#pragma unroll
    for (int r = 0; r < 32; r += 8) {
        const int x = x0 + tr + r;
        tile[tr + r][tx] = in[((((n << 6) + y) * 64) + x) * C + c0 + tx]; // tile[x][c]
    }
    __syncthreads();
#pragma unroll
    for (int r = 0; r < 32; r += 8) {
        const int c = c0 + tr + r;
        out[(((n * C + c) << 6) + y) * 64 + x0 + tx] = tile[tx][tr + r];
    }
}

// w[cout][cin][kh][kw] -> wt[(k*Cin+ci)*Cout + co]
__global__ __launch_bounds__(256) void transpose_w(const float* __restrict__ w,
                                                   float* __restrict__ wt,
                                                   int Cin, int Cout, int KK, int total) {
    const int idx = blockIdx.x * 256 + threadIdx.x;
    if (idx >= total) return;
    const int co = idx % Cout;
    const int r = idx / Cout;
    const int ci = r % Cin;
    const int k = r / Cin;
    wt[idx] = w[(co * Cin + ci) * KK + k];
}

// Deformable conv layer, NHWC in/out, fused bias+ReLU.
// grid: (2, 64, N); block 256. Tile = 32 pixels (half row) x COUT.
template <int K, int CIN, int COUT>
__global__ __launch_bounds__(256) void dconv(const float* __restrict__ in,
                                             const float* __restrict__ off,
                                             const float* __restrict__ wt,
                                             const float* __restrict__ bias,
                                             float* __restrict__ out) {
    constexpr int PAD = (K == 3) ? 1 : 0;
    constexpr int NCHUNK = CIN / 128;
    constexpr int NCO = COUT / 32; // couts per thread (4 or 8)
    __shared__ float s[128][32];   // s[ci_local][px], 16 KB

    const int t = threadIdx.x;
    const int n = blockIdx.z;
    const int y = blockIdx.y;
    const int x0 = blockIdx.x << 5;

    // staging role: 1 pixel, 16 channels per chunk
    const int s_px = t & 31;
    const int s_ci0 = (t >> 5) << 4;
    const int xg = x0 + s_px;

    // fma role: 4 consecutive pixels, NCO consecutive couts
    const int f_px = (t & 7) << 2;
    const int f_co = (t >> 3) * NCO;

    float acc[4][NCO];
#pragma unroll
    for (int p = 0; p < 4; ++p)
#pragma unroll
        for (int j = 0; j < NCO; ++j) acc[p][j] = 0.f;

    const int offbase = ((n * 2 * K * K) * 64 + y) * 64 + xg;

    for (int k = 0; k < K * K; ++k) {
        const int kh = k / K, kw = k - kh * K;
        const float dy = off[offbase + (2 * k) * 4096];
        const float dx = off[offbase + (2 * k + 1) * 4096];
        const float py = (float)(y + kh - PAD) + dy;
        const float pxc = (float)(xg + kw - PAD) + dx;
        const float y0f = floorf(py), x0f = floorf(pxc);
        const int iy0 = (int)y0f, ix0 = (int)x0f;
        const int iy1 = iy0 + 1, ix1 = ix0 + 1;
        const float wy1 = py - y0f, wy0 = 1.f - wy1;
        const float wx1 = pxc - x0f, wx0 = 1.f - wx1;
        const bool vy0 = (iy0 >= 0) & (iy0 < 64);
        const bool vy1 = (iy1 >= 0) & (iy1 < 64);
        const bool vx0 = (ix0 >= 0) & (ix0 < 64);
        const bool vx1 = (ix1 >= 0) & (ix1 < 64);
        const float w00 = (vy0 & vx0) ? wy0 * wx0 : 0.f;
        const float w01 = (vy0 & vx1) ? wy0 * wx1 : 0.f;
        const float w10 = (vy1 & vx0) ? wy1 * wx0 : 0.f;
        const float w11 = (vy1 & vx1) ? wy1 * wx1 : 0.f;
        const int cy0 = min(max(iy0, 0), 63), cy1 = min(max(iy1, 0), 63);
        const int cx0 = min(max(ix0, 0), 63), cx1 = min(max(ix1, 0), 63);
        const float* p00 = in + (size_t)(((n << 6) + cy0) * 64 + cx0) * CIN;
        const float* p01 = in + (size_t)(((n << 6) + cy0) * 64 + cx1) * CIN;
        const float* p10 = in + (size_t)(((n << 6) + cy1) * 64 + cx0) * CIN;
        const float* p11 = in + (size_t)(((n << 6) + cy1) * 64 + cx1) * CIN;

        for (int c = 0; c < NCHUNK; ++c) {
            __syncthreads(); // previous chunk's FMA reads done
            const int cib = c * 128 + s_ci0;
#pragma unroll
            for (int jj = 0; jj < 4; ++jj) {
                const float4 a = *(const float4*)(p00 + cib + jj * 4);
                const float4 b = *(const float4*)(p01 + cib + jj * 4);
                const float4 cc = *(const float4*)(p10 + cib + jj * 4);
                const float4 d = *(const float4*)(p11 + cib + jj * 4);
                s[s_ci0 + jj * 4 + 0][s_px] = w00 * a.x + w01 * b.x + w10 * cc.x + w11 * d.x;
                s[s_ci0 + jj * 4 + 1][s_px] = w00 * a.y + w01 * b.y + w10 * cc.y + w11 * d.y;
                s[s_ci0 + jj * 4 + 2][s_px] = w00 * a.z + w01 * b.z + w10 * cc.z + w11 * d.z;
                s[s_ci0 + jj * 4 + 3][s_px] = w00 * a.w + w01 * b.w + w10 * cc.w + w11 * d.w;
            }
            __syncthreads();
            const float* wbase = wt + (size_t)(k * CIN + c * 128) * COUT + f_co;
#pragma unroll 4
            for (int ci = 0; ci < 128; ++ci) {
                const float4 sv = *(const float4*)&s[ci][f_px];
#pragma unroll
                for (int j4 = 0; j4 < NCO / 4; ++j4) {
                    const float4 wv = *(const float4*)(wbase + ci * COUT + j4 * 4);
                    acc[0][j4 * 4 + 0] += sv.x * wv.x;
                    acc[0][j4 * 4 + 1] += sv.x * wv.y;
                    acc[0][j4 * 4 + 2] += sv.x * wv.z;
                    acc[0][j4 * 4 + 3] += sv.x * wv.w;
                    acc[1][j4 * 4 + 0] += sv.y * wv.x;
                    acc[1][j4 * 4 + 1] += sv.y * wv.y;
                    acc[1][j4 * 4 + 2] += sv.y * wv.z;
                    acc[1][j4 * 4 + 3] += sv.y * wv.w;
                    acc[2][j4 * 4 + 0] += sv.z * wv.x;
                    acc[2][j4 * 4 + 1] += sv.z * wv.y;
                    acc[2][j4 * 4 + 2] += sv.z * wv.z;
                    acc[2][j4 * 4 + 3] += sv.z * wv.w;
                    acc[3][j4 * 4 + 0] += sv.w * wv.x;
                    acc[3][j4 * 4 + 1] += sv.w * wv.y;
                    acc[3][j4 * 4 + 2] += sv.w * wv.z;
                    acc[3][j4 * 4 + 3] += sv.w * wv.w;
                }
            }
        }
    }

    const int pix0 = (((n << 6) + y) << 6) + x0;
#pragma unroll
    for (int j4 = 0; j4 < NCO / 4; ++j4) {
        const float4 bv = *(const float4*)(bias + f_co + j4 * 4);
#pragma unroll
        for (int p = 0; p < 4; ++p) {
            float4 o;
            o.x = fmaxf(acc[p][j4 * 4 + 0] + bv.x, 0.f);
            o.y = fmaxf(acc[p][j4 * 4 + 1] + bv.y, 0.f);
            o.z = fmaxf(acc[p][j4 * 4 + 2] + bv.z, 0.f);
            o.w = fmaxf(acc[p][j4 * 4 + 3] + bv.w, 0.f);
            *(float4*)(out + (size_t)(pix0 + f_px + p) * COUT + f_co + j4 * 4) = o;
        }
    }
}

extern "C" void kernel_launch(void* const* d_in, const int* in_sizes, int n_in,
                              void* d_out, int out_size, void* d_ws, size_t ws_size,
                              hipStream_t stream) {
    (void)in_sizes; (void)n_in; (void)out_size; (void)ws_size;
    const float* x = (const float*)d_in[0];
    const float* offs[8];
    const float* wsrc[8];
    const float* bs[8];
    for (int i = 0; i < 8; ++i) {
        offs[i] = (const float*)d_in[1 + i];
        wsrc[i] = (const float*)d_in[9 + 2 * i];
        bs[i] = (const float*)d_in[10 + 2 * i];
    }
    // workspace layout: bufA 32MB | bufB 16MB | wt 5.25MB   (total ~53MB)
    float* bufA = (float*)d_ws;
    float* bufB = (float*)((char*)d_ws + 33554432u);
    float* wt = (float*)((char*)d_ws + 50331648u);
    const size_t wo[8] = {0, 131072, 425984, 573440, 720896, 868352, 1015808, 1163264};
    const int cins[8] = {512, 256, 128, 128, 128, 128, 128, 128};
    const int couts[8] = {256, 128, 128, 128, 128, 128, 128, 128};
    const int kks[8] = {1, 9, 9, 9, 9, 9, 9, 9};

    nchw2nhwc<<<dim3((512 / 32) * 2, 64, 4), 256, 0, stream>>>(x, bufA, 512);
    for (int i = 0; i < 8; ++i) {
        const int total = couts[i] * cins[i] * kks[i];
        transpose_w<<<(total + 255) / 256, 256, 0, stream>>>(wsrc[i], wt + wo[i],
                                                             cins[i], couts[i], kks[i], total);
    }
    const dim3 cgrid(2, 64, 4);
    dconv<1, 512, 256><<<cgrid, 256, 0, stream>>>(bufA, offs[0], wt + wo[0], bs[0], bufB);
    dconv<3, 256, 128><<<cgrid, 256, 0, stream>>>(bufB, offs[1], wt + wo[1], bs[1], bufA);
    dconv<3, 128, 128><<<cgrid, 256, 0, stream>>>(bufA, offs[2], wt + wo[2], bs[2], bufB);
    dconv<3, 128, 128><<<cgrid, 256, 0, stream>>>(bufB, offs[3], wt + wo[3], bs[3], bufA);
    dconv<3, 128, 128><<<cgrid, 256, 0, stream>>>(bufA, offs[4], wt + wo[4], bs[4], bufB);
    dconv<3, 128, 128><<<cgrid, 256, 0, stream>>>(bufB, offs[5], wt + wo[5], bs[5], bufA);
    dconv<3, 128, 128><<<cgrid, 256, 0, stream>>>(bufA, offs[6], wt + wo[6], bs[6], bufB);
    dconv<3, 128, 128><<<cgrid, 256, 0, stream>>>(bufB, offs[7], wt + wo[7], bs[7], bufA);
    nhwc2nchw<<<dim3((128 / 32) * 2, 64, 4), 256, 0, stream>>>(bufA, (float*)d_out, 128);
}

// Round 2
// 539.913 us; speedup vs baseline: 2.0015x; 2.0015x over previous
//
#include <hip/hip_runtime.h>

typedef _Float16 f16x8 __attribute__((ext_vector_type(8)));
typedef float f32x4 __attribute__((ext_vector_type(4)));

// ---------------------------------------------------------------------------
// DeformConv stack: 8 layers, N=4, H=W=64.
// L0 (512->256, k=1), L1 (256->128, 3x3), L2..L7 (128->128, 3x3)
// fp16x2-split MFMA GEMM (hi*hi + hi*lo + lo*hi), fp32 NHWC activations,
// bilinear im2col staged per 32-channel chunk into LDS.
// ---------------------------------------------------------------------------

// NCHW -> NHWC tile transpose. grid: ((C/32)*2, 64, N), block 256.
__global__ __launch_bounds__(256) void nchw2nhwc(const float* __restrict__ in,
                                                 float* __restrict__ out, int C) {
    const int ctiles = C >> 5;
    const int ct = blockIdx.x % ctiles;
    const int xt = blockIdx.x / ctiles;
    const int y = blockIdx.y, n = blockIdx.z;
    const int c0 = ct * 32, x0 = xt * 32;
    __shared__ float tile[32][33];
    const int tx = threadIdx.x & 31, tr = threadIdx.x >> 5;
#pragma unroll
    for (int r = 0; r < 32; r += 8) {
        const int c = c0 + tr + r;
        tile[tr + r][tx] = in[(((n * C + c) << 6) + y) * 64 + x0 + tx]; // tile[c][x]
    }
    __syncthreads();
#pragma unroll
    for (int r = 0; r < 32; r += 8) {
        const int x = x0 + tr + r;
        out[((((n << 6) + y) * 64) + x) * C + c0 + tx] = tile[tx][tr + r];
    }
}

// NHWC -> NCHW tile transpose. grid: ((C/32)*2, 64, N), block 256.
__global__ __launch_bounds__(256) void nhwc2nchw(const float* __restrict__ in,
                                                 float* __restrict__ out, int C) {
    const int ctiles = C >> 5;
    const int ct = blockIdx.x % ctiles;
    const int xt = blockIdx.x / ctiles;
    const int y = blockIdx.y, n = blockIdx.z;
    const int c0 = ct * 32, x0 = xt * 32;
    __shared__ float tile[32][33];
    const int tx = threadIdx.x & 31, tr = threadIdx.x >> 5;
#pragma unroll
    for (int r = 0; r < 32; r += 8) {
        const int x = x0 + tr + r;
        tile[tr + r][tx] = in[((((n << 6) + y) * 64) + x) * C + c0 + tx]; // tile[x][c]
    }
    __syncthreads();
#pragma unroll
    for (int r = 0; r < 32; r += 8) {
        const int c = c0 + tr + r;
        out[(((n * C + c) << 6) + y) * 64 + x0 + tx] = tile[tx][tr + r];
    }
}

// w[cout][cin][kh][kw] fp32 -> wt rows of 64 halves: [k][chunk][co][ hi(32) | lo(32) ]
__global__ __launch_bounds__(256) void prep_w(const float* __restrict__ w,
                                              _Float16* __restrict__ wt,
                                              int CIN, int COUT, int KK, int total) {
    const int idx = blockIdx.x * 256 + threadIdx.x;
    if (idx >= total) return;
    const int e = idx & 31;
    int r = idx >> 5;
    const int co = r % COUT;
    r /= COUT;
    const int nc = CIN >> 5;
    const int c = r % nc;
    const int k = r / nc;
    const int ci = c * 32 + e;
    const float v = w[(co * CIN + ci) * KK + k];
    const _Float16 h = (_Float16)v;
    const _Float16 l = (_Float16)(v - (float)h);
    const size_t row = ((size_t)(k * nc + c) * COUT + co) * 64;
    wt[row + e] = h;
    wt[row + 32 + e] = l;
}

// Deformable conv layer. grid: (256, COUTF/128), block 256 (4 waves).
// Block tile: 64 px (one image row) x 128 couts. Wave: 32 px x 64 co.
template <int TAPS, int CIN, int COUTF>
__global__ __launch_bounds__(256) void dconv_mfma(const float* __restrict__ in,
                                                  const float* __restrict__ off,
                                                  const _Float16* __restrict__ wt,
                                                  const float* __restrict__ bias,
                                                  float* __restrict__ out) {
    constexpr int KS = (TAPS == 9) ? 3 : 1;
    constexpr int PAD = (TAPS == 9) ? 1 : 0;
    constexpr int NC = CIN / 32;          // 32-channel chunks
    constexpr int TOTAL_IT = TAPS * NC;

    // padded tiles: stride 40 halves (80 B) -> <=2-way bank aliasing (free)
    __shared__ __align__(16) _Float16 sAh[64 * 40];
    __shared__ __align__(16) _Float16 sAl[64 * 40];
    __shared__ __align__(16) _Float16 sBh[128 * 40];
    __shared__ __align__(16) _Float16 sBl[128 * 40];

    const int t = threadIdx.x;
    const int bx = blockIdx.x;     // 0..255 -> (n, y)
    const int coy = blockIdx.y;    // 128-co tile
    const int n = bx >> 6, y = bx & 63;

    // staging roles
    const int px = t & 63;         // x coordinate / A row
    const int cg = t >> 6;         // 8-ci group (0..3) within chunk
    const int bco = t >> 1;        // B row 0..127
    const int bh = t & 1;          // half of B row

    // mfma roles
    const int lane = t & 63, wv = t >> 6;
    const int wm = wv & 1, wn = wv >> 1;
    const int l15 = lane & 15, lq = lane >> 4;

    // bilinear state for current tap
    float w00, w01, w10, w11;
    const float *p00, *p01, *p10, *p11;

    auto mkcoef = [&](int k, float dy, float dx) {
        const int kh = k / KS, kw = k - kh * KS;
        const float py = (float)(y + kh - PAD) + dy;
        const float pxc = (float)(px + kw - PAD) + dx;
        const float y0f = floorf(py), x0f = floorf(pxc);
        const int iy0 = (int)y0f, ix0 = (int)x0f;
        const int iy1 = iy0 + 1, ix1 = ix0 + 1;
        const float wy1 = py - y0f, wy0 = 1.f - wy1;
        const float wx1 = pxc - x0f, wx0 = 1.f - wx1;
        const bool vy0 = (iy0 >= 0) & (iy0 < 64), vy1 = (iy1 >= 0) & (iy1 < 64);
        const bool vx0 = (ix0 >= 0) & (ix0 < 64), vx1 = (ix1 >= 0) & (ix1 < 64);
        w00 = (vy0 & vx0) ? wy0 * wx0 : 0.f;
        w01 = (vy0 & vx1) ? wy0 * wx1 : 0.f;
        w10 = (vy1 & vx0) ? wy1 * wx0 : 0.f;
        w11 = (vy1 & vx1) ? wy1 * wx1 : 0.f;
        const int cy0 = min(max(iy0, 0), 63), cy1 = min(max(iy1, 0), 63);
        const int cx0 = min(max(ix0, 0), 63), cx1 = min(max(ix1, 0), 63);
        p00 = in + (size_t)(((n << 6) + cy0) * 64 + cx0) * CIN + cg * 8;
        p01 = in + (size_t)(((n << 6) + cy0) * 64 + cx1) * CIN + cg * 8;
        p10 = in + (size_t)(((n << 6) + cy1) * 64 + cx0) * CIN + cg * 8;
        p11 = in + (size_t)(((n << 6) + cy1) * 64 + cx1) * CIN + cg * 8;
    };

    auto oidx = [&](int k) { return ((n * 2 * TAPS + 2 * k) * 64 + y) * 64 + px; };

    // prefetch registers (next chunk)
    float4 A00, A01, A10, A11, A20, A21, A30, A31;
    uint4 B0, B1, B2, B3;

    auto load_chunk = [&](int k, int c) {
        const float* q0 = p00 + c * 32;
        const float* q1 = p01 + c * 32;
        const float* q2 = p10 + c * 32;
        const float* q3 = p11 + c * 32;
        A00 = *(const float4*)q0; A01 = *(const float4*)(q0 + 4);
        A10 = *(const float4*)q1; A11 = *(const float4*)(q1 + 4);
        A20 = *(const float4*)q2; A21 = *(const float4*)(q2 + 4);
        A30 = *(const float4*)q3; A31 = *(const float4*)(q3 + 4);
        const size_t brow = ((size_t)(k * NC + c) * COUTF + coy * 128 + bco) * 64;
        const uint4* bp = (const uint4*)(wt + brow);
        B0 = bp[bh * 2]; B1 = bp[bh * 2 + 1];     // hi half-row (32 B)
        B2 = bp[4 + bh * 2]; B3 = bp[5 + bh * 2]; // lo half-row (32 B)
    };

    auto write_chunk = [&]() {
        float v[8];
        v[0] = w00 * A00.x + w01 * A10.x + w10 * A20.x + w11 * A30.x;
        v[1] = w00 * A00.y + w01 * A10.y + w10 * A20.y + w11 * A30.y;
        v[2] = w00 * A00.z + w01 * A10.z + w10 * A20.z + w11 * A30.z;
        v[3] = w00 * A00.w + w01 * A10.w + w10 * A20.w + w11 * A30.w;
        v[4] = w00 * A01.x + w01 * A11.x + w10 * A21.x + w11 * A31.x;
        v[5] = w00 * A01.y + w01 * A11.y + w10 * A21.y + w11 * A31.y;
        v[6] = w00 * A01.z + w01 * A11.z + w10 * A21.z + w11 * A31.z;
        v[7] = w00 * A01.w + w01 * A11.w + w10 * A21.w + w11 * A31.w;
        f16x8 hv, lv;
#pragma unroll
        for (int j = 0; j < 8; ++j) {
            const _Float16 h = (_Float16)v[j];
            hv[j] = h;
            lv[j] = (_Float16)(v[j] - (float)h);
        }
        *(f16x8*)&sAh[px * 40 + cg * 8] = hv;
        *(f16x8*)&sAl[px * 40 + cg * 8] = lv;
        *(uint4*)&sBh[bco * 40 + bh * 16] = B0;
        *(uint4*)&sBh[bco * 40 + bh * 16 + 8] = B1;
        *(uint4*)&sBl[bco * 40 + bh * 16] = B2;
        *(uint4*)&sBl[bco * 40 + bh * 16 + 8] = B3;
    };

    // prologue
    float dyc = off[oidx(0)];
    float dxc = off[oidx(0) + 4096];
    mkcoef(0, dyc, dxc);
    float dyn = 0.f, dxn = 0.f;
    if (TAPS > 1) { dyn = off[oidx(1)]; dxn = off[oidx(1) + 4096]; }
    load_chunk(0, 0);

    f32x4 acc[2][4] = {};

    int k = 0, c = 0;
    for (int it = 0; it < TOTAL_IT; ++it) {
        __syncthreads();              // previous MFMA done reading LDS
        write_chunk();                // stage current chunk (regs -> LDS)
        if (it + 1 < TOTAL_IT) {
            int c2 = c + 1, k2 = k;
            if (c2 == NC) {
                c2 = 0; k2 = k + 1;
                mkcoef(k2, dyn, dxn);
                if (k2 + 1 < TAPS) { dyn = off[oidx(k2 + 1)]; dxn = off[oidx(k2 + 1) + 4096]; }
            }
            load_chunk(k2, c2);       // issue next-chunk loads BEFORE MFMA
            k = k2; c = c2;
        }
        __syncthreads();              // staged data visible

        f16x8 ah[2], al[2], bhv[4], blv[4];
#pragma unroll
        for (int mi = 0; mi < 2; ++mi) {
            const int ar = wm * 32 + mi * 16 + l15;
            ah[mi] = *(const f16x8*)&sAh[ar * 40 + lq * 8];
            al[mi] = *(const f16x8*)&sAl[ar * 40 + lq * 8];
        }
#pragma unroll
        for (int ni = 0; ni < 4; ++ni) {
            const int br = wn * 64 + ni * 16 + l15;
            bhv[ni] = *(const f16x8*)&sBh[br * 40 + lq * 8];
            blv[ni] = *(const f16x8*)&sBl[br * 40 + lq * 8];
        }
#pragma unroll
        for (int mi = 0; mi < 2; ++mi)
#pragma unroll
            for (int ni = 0; ni < 4; ++ni) {
                acc[mi][ni] = __builtin_amdgcn_mfma_f32_16x16x32_f16(ah[mi], bhv[ni], acc[mi][ni], 0, 0, 0);
                acc[mi][ni] = __builtin_amdgcn_mfma_f32_16x16x32_f16(ah[mi], blv[ni], acc[mi][ni], 0, 0, 0);
                acc[mi][ni] = __builtin_amdgcn_mfma_f32_16x16x32_f16(al[mi], bhv[ni], acc[mi][ni], 0, 0, 0);
            }
    }

    // epilogue: bias + ReLU, fp32 NHWC store
    const size_t pixbase = (size_t)bx * 64;
#pragma unroll
    for (int ni = 0; ni < 4; ++ni) {
        const int co = coy * 128 + wn * 64 + ni * 16 + l15;
        const float bv = bias[co];
#pragma unroll
        for (int mi = 0; mi < 2; ++mi) {
#pragma unroll
            for (int r = 0; r < 4; ++r) {
                const int pxl = wm * 32 + mi * 16 + lq * 4 + r;
                out[(pixbase + pxl) * COUTF + co] = fmaxf(acc[mi][ni][r] + bv, 0.f);
            }
        }
    }
}

extern "C" void kernel_launch(void* const* d_in, const int* in_sizes, int n_in,
                              void* d_out, int out_size, void* d_ws, size_t ws_size,
                              hipStream_t stream) {
    (void)in_sizes; (void)n_in; (void)out_size; (void)ws_size;
    const float* x = (const float*)d_in[0];
    const float* offs[8];
    const float* wsrc[8];
    const float* bs[8];
    for (int i = 0; i < 8; ++i) {
        offs[i] = (const float*)d_in[1 + i];
        wsrc[i] = (const float*)d_in[9 + 2 * i];
        bs[i] = (const float*)d_in[10 + 2 * i];
    }
    // workspace: bufA 32MB | bufB 16MB | wt (fp16 hi/lo) 5.25MB
    float* bufA = (float*)d_ws;
    float* bufB = (float*)((char*)d_ws + 33554432u);
    _Float16* wt = (_Float16*)((char*)d_ws + 50331648u);
    // per-layer offsets into wt, in halves
    const size_t wo[8] = {0, 262144, 851968, 1146880, 1441792, 1736704, 2031616, 2326528};
    const int cins[8] = {512, 256, 128, 128, 128, 128, 128, 128};
    const int couts[8] = {256, 128, 128, 128, 128, 128, 128, 128};
    const int kks[8] = {1, 9, 9, 9, 9, 9, 9, 9};

    nchw2nhwc<<<dim3((512 / 32) * 2, 64, 4), 256, 0, stream>>>(x, bufA, 512);
    for (int i = 0; i < 8; ++i) {
        const int total = kks[i] * cins[i] * couts[i];
        prep_w<<<(total + 255) / 256, 256, 0, stream>>>(wsrc[i], wt + wo[i],
                                                        cins[i], couts[i], kks[i], total);
    }
    dconv_mfma<1, 512, 256><<<dim3(256, 2), 256, 0, stream>>>(bufA, offs[0], wt + wo[0], bs[0], bufB);
    dconv_mfma<9, 256, 128><<<dim3(256, 1), 256, 0, stream>>>(bufB, offs[1], wt + wo[1], bs[1], bufA);
    dconv_mfma<9, 128, 128><<<dim3(256, 1), 256, 0, stream>>>(bufA, offs[2], wt + wo[2], bs[2], bufB);
    dconv_mfma<9, 128, 128><<<dim3(256, 1), 256, 0, stream>>>(bufB, offs[3], wt + wo[3], bs[3], bufA);
    dconv_mfma<9, 128, 128><<<dim3(256, 1), 256, 0, stream>>>(bufA, offs[4], wt + wo[4], bs[4], bufB);
    dconv_mfma<9, 128, 128><<<dim3(256, 1), 256, 0, stream>>>(bufB, offs[5], wt + wo[5], bs[5], bufA);
    dconv_mfma<9, 128, 128><<<dim3(256, 1), 256, 0, stream>>>(bufA, offs[6], wt + wo[6], bs[6], bufB);
    dconv_mfma<9, 128, 128><<<dim3(256, 1), 256, 0, stream>>>(bufB, offs[7], wt + wo[7], bs[7], bufA);
    nhwc2nchw<<<dim3((128 / 32) * 2, 64, 4), 256, 0, stream>>>(bufA, (float*)d_out, 128);
}

// Round 6
// 514.546 us; speedup vs baseline: 2.1001x; 1.0493x over previous
//
#include <hip/hip_runtime.h>

typedef _Float16 f16x8 __attribute__((ext_vector_type(8)));
typedef float f32x4 __attribute__((ext_vector_type(4)));

// ---------------------------------------------------------------------------
// DeformConv stack: 8 layers, N=4, H=W=64.
// L0 (512->256, k=1), L1 (256->128, 3x3), L2..L7 (128->128, 3x3)
// ROUND-2 SOURCE VERBATIM (the proven-passing kernel), with exactly ONE
// change: bijective XCD-chunked swizzle of blockIdx.x in dconv_mfma.
// This is a controlled experiment: the swizzle relabels independent blocks
// and cannot change any computed value, so output must be bit-identical
// to round 2 (absmax 0.009765625) unless a scheduling-dependent race exists.
// ---------------------------------------------------------------------------

__global__ __launch_bounds__(256) void nchw2nhwc(const float* __restrict__ in,
                                                 float* __restrict__ out, int C) {
    const int ctiles = C >> 5;
    const int ct = blockIdx.x % ctiles;
    const int xt = blockIdx.x / ctiles;
    const int y = blockIdx.y, n = blockIdx.z;
    const int c0 = ct * 32, x0 = xt * 32;
    __shared__ float tile[32][33];
    const int tx = threadIdx.x & 31, tr = threadIdx.x >> 5;
#pragma unroll
    for (int r = 0; r < 32; r += 8) {
        const int c = c0 + tr + r;
        tile[tr + r][tx] = in[(((n * C + c) << 6) + y) * 64 + x0 + tx]; // tile[c][x]
    }
    __syncthreads();
#pragma unroll
    for (int r = 0; r < 32; r += 8) {
        const int x = x0 + tr + r;
        out[((((n << 6) + y) * 64) + x) * C + c0 + tx] = tile[tx][tr + r];
    }
}

__global__ __launch_bounds__(256) void nhwc2nchw(const float* __restrict__ in,
                                                 float* __restrict__ out, int C) {
    const int ctiles = C >> 5;
    const int ct = blockIdx.x % ctiles;
    const int xt = blockIdx.x / ctiles;
    const int y = blockIdx.y, n = blockIdx.z;
    const int c0 = ct * 32, x0 = xt * 32;
    __shared__ float tile[32][33];
    const int tx = threadIdx.x & 31, tr = threadIdx.x >> 5;
#pragma unroll
    for (int r = 0; r < 32; r += 8) {
        const int x = x0 + tr + r;
        tile[tr + r][tx] = in[((((n << 6) + y) * 64) + x) * C + c0 + tx]; // tile[x][c]
    }
    __syncthreads();
#pragma unroll
    for (int r = 0; r < 32; r += 8) {
        const int c = c0 + tr + r;
        out[(((n * C + c) << 6) + y) * 64 + x0 + tx] = tile[tx][tr + r];
    }
}

// w[cout][cin][kh][kw] fp32 -> wt rows of 64 halves: [k][chunk][co][ hi(32) | lo(32) ]
__global__ __launch_bounds__(256) void prep_w(const float* __restrict__ w,
                                              _Float16* __restrict__ wt,
                                              int CIN, int COUT, int KK, int total) {
    const int idx = blockIdx.x * 256 + threadIdx.x;
    if (idx >= total) return;
    const int e = idx & 31;
    int r = idx >> 5;
    const int co = r % COUT;
    r /= COUT;
    const int nc = CIN >> 5;
    const int c = r % nc;
    const int k = r / nc;
    const int ci = c * 32 + e;
    const float v = w[(co * CIN + ci) * KK + k];
    const _Float16 h = (_Float16)v;
    const _Float16 l = (_Float16)(v - (float)h);
    const size_t row = ((size_t)(k * nc + c) * COUT + co) * 64;
    wt[row + e] = h;
    wt[row + 32 + e] = l;
}

// Deformable conv layer. grid: (256, COUTF/128), block 256 (4 waves).
// Block tile: 64 px (one image row) x 128 couts. Wave: 32 px x 64 co.
template <int TAPS, int CIN, int COUTF>
__global__ __launch_bounds__(256) void dconv_mfma(const float* __restrict__ in,
                                                  const float* __restrict__ off,
                                                  const _Float16* __restrict__ wt,
                                                  const float* __restrict__ bias,
                                                  float* __restrict__ out) {
    constexpr int KS = (TAPS == 9) ? 3 : 1;
    constexpr int PAD = (TAPS == 9) ? 1 : 0;
    constexpr int NC = CIN / 32;          // 32-channel chunks
    constexpr int TOTAL_IT = TAPS * NC;

    // padded tiles: stride 40 halves (80 B)
    __shared__ __align__(16) _Float16 sAh[64 * 40];
    __shared__ __align__(16) _Float16 sAl[64 * 40];
    __shared__ __align__(16) _Float16 sBh[128 * 40];
    __shared__ __align__(16) _Float16 sBl[128 * 40];

    const int t = threadIdx.x;
    const int bx0 = blockIdx.x;
    const int bx = (bx0 & 7) * 32 + (bx0 >> 3); // THE ONLY CHANGE vs round 2:
                                                // bijective XCD swizzle (256=8*32)
    const int coy = blockIdx.y;    // 128-co tile
    const int n = bx >> 6, y = bx & 63;

    // staging roles
    const int px = t & 63;         // x coordinate / A row
    const int cg = t >> 6;         // 8-ci group (0..3) within chunk
    const int bco = t >> 1;        // B row 0..127
    const int bh = t & 1;          // half of B row

    // mfma roles
    const int lane = t & 63, wv = t >> 6;
    const int wm = wv & 1, wn = wv >> 1;
    const int l15 = lane & 15, lq = lane >> 4;

    // bilinear state for current tap
    float w00, w01, w10, w11;
    const float *p00, *p01, *p10, *p11;

    auto mkcoef = [&](int k, float dy, float dx) {
        const int kh = k / KS, kw = k - kh * KS;
        const float py = (float)(y + kh - PAD) + dy;
        const float pxc = (float)(px + kw - PAD) + dx;
        const float y0f = floorf(py), x0f = floorf(pxc);
        const int iy0 = (int)y0f, ix0 = (int)x0f;
        const int iy1 = iy0 + 1, ix1 = ix0 + 1;
        const float wy1 = py - y0f, wy0 = 1.f - wy1;
        const float wx1 = pxc - x0f, wx0 = 1.f - wx1;
        const bool vy0 = (iy0 >= 0) & (iy0 < 64), vy1 = (iy1 >= 0) & (iy1 < 64);
        const bool vx0 = (ix0 >= 0) & (ix0 < 64), vx1 = (ix1 >= 0) & (ix1 < 64);
        w00 = (vy0 & vx0) ? wy0 * wx0 : 0.f;
        w01 = (vy0 & vx1) ? wy0 * wx1 : 0.f;
        w10 = (vy1 & vx0) ? wy1 * wx0 : 0.f;
        w11 = (vy1 & vx1) ? wy1 * wx1 : 0.f;
        const int cy0 = min(max(iy0, 0), 63), cy1 = min(max(iy1, 0), 63);
        const int cx0 = min(max(ix0, 0), 63), cx1 = min(max(ix1, 0), 63);
        p00 = in + (size_t)(((n << 6) + cy0) * 64 + cx0) * CIN + cg * 8;
        p01 = in + (size_t)(((n << 6) + cy0) * 64 + cx1) * CIN + cg * 8;
        p10 = in + (size_t)(((n << 6) + cy1) * 64 + cx0) * CIN + cg * 8;
        p11 = in + (size_t)(((n << 6) + cy1) * 64 + cx1) * CIN + cg * 8;
    };

    auto oidx = [&](int k) { return ((n * 2 * TAPS + 2 * k) * 64 + y) * 64 + px; };

    // prefetch registers (next chunk)
    float4 A00, A01, A10, A11, A20, A21, A30, A31;
    uint4 B0, B1, B2, B3;

    auto load_chunk = [&](int k, int c) {
        const float* q0 = p00 + c * 32;
        const float* q1 = p01 + c * 32;
        const float* q2 = p10 + c * 32;
        const float* q3 = p11 + c * 32;
        A00 = *(const float4*)q0; A01 = *(const float4*)(q0 + 4);
        A10 = *(const float4*)q1; A11 = *(const float4*)(q1 + 4);
        A20 = *(const float4*)q2; A21 = *(const float4*)(q2 + 4);
        A30 = *(const float4*)q3; A31 = *(const float4*)(q3 + 4);
        const size_t brow = ((size_t)(k * NC + c) * COUTF + coy * 128 + bco) * 64;
        const uint4* bp = (const uint4*)(wt + brow);
        B0 = bp[bh * 2]; B1 = bp[bh * 2 + 1];     // hi half-row (32 B)
        B2 = bp[4 + bh * 2]; B3 = bp[5 + bh * 2]; // lo half-row (32 B)
    };

    auto write_chunk = [&]() {
        float v[8];
        v[0] = w00 * A00.x + w01 * A10.x + w10 * A20.x + w11 * A30.x;
        v[1] = w00 * A00.y + w01 * A10.y + w10 * A20.y + w11 * A30.y;
        v[2] = w00 * A00.z + w01 * A10.z + w10 * A20.z + w11 * A30.z;
        v[3] = w00 * A00.w + w01 * A10.w + w10 * A20.w + w11 * A30.w;
        v[4] = w00 * A01.x + w01 * A11.x + w10 * A21.x + w11 * A31.x;
        v[5] = w00 * A01.y + w01 * A11.y + w10 * A21.y + w11 * A31.y;
        v[6] = w00 * A01.z + w01 * A11.z + w10 * A21.z + w11 * A31.z;
        v[7] = w00 * A01.w + w01 * A11.w + w10 * A21.w + w11 * A31.w;
        f16x8 hv, lv;
#pragma unroll
        for (int j = 0; j < 8; ++j) {
            const _Float16 h = (_Float16)v[j];
            hv[j] = h;
            lv[j] = (_Float16)(v[j] - (float)h);
        }
        *(f16x8*)&sAh[px * 40 + cg * 8] = hv;
        *(f16x8*)&sAl[px * 40 + cg * 8] = lv;
        *(uint4*)&sBh[bco * 40 + bh * 16] = B0;
        *(uint4*)&sBh[bco * 40 + bh * 16 + 8] = B1;
        *(uint4*)&sBl[bco * 40 + bh * 16] = B2;
        *(uint4*)&sBl[bco * 40 + bh * 16 + 8] = B3;
    };

    // prologue
    float dyc = off[oidx(0)];
    float dxc = off[oidx(0) + 4096];
    mkcoef(0, dyc, dxc);
    float dyn = 0.f, dxn = 0.f;
    if (TAPS > 1) { dyn = off[oidx(1)]; dxn = off[oidx(1) + 4096]; }
    load_chunk(0, 0);

    f32x4 acc[2][4] = {};

    int k = 0, c = 0;
    for (int it = 0; it < TOTAL_IT; ++it) {
        __syncthreads();              // previous MFMA done reading LDS
        write_chunk();                // stage current chunk (regs -> LDS)
        if (it + 1 < TOTAL_IT) {
            int c2 = c + 1, k2 = k;
            if (c2 == NC) {
                c2 = 0; k2 = k + 1;
                mkcoef(k2, dyn, dxn);
                if (k2 + 1 < TAPS) { dyn = off[oidx(k2 + 1)]; dxn = off[oidx(k2 + 1) + 4096]; }
            }
            load_chunk(k2, c2);       // issue next-chunk loads BEFORE MFMA
            k = k2; c = c2;
        }
        __syncthreads();              // staged data visible

        f16x8 ah[2], al[2], bhv[4], blv[4];
#pragma unroll
        for (int mi = 0; mi < 2; ++mi) {
            const int ar = wm * 32 + mi * 16 + l15;
            ah[mi] = *(const f16x8*)&sAh[ar * 40 + lq * 8];
            al[mi] = *(const f16x8*)&sAl[ar * 40 + lq * 8];
        }
#pragma unroll
        for (int ni = 0; ni < 4; ++ni) {
            const int br = wn * 64 + ni * 16 + l15;
            bhv[ni] = *(const f16x8*)&sBh[br * 40 + lq * 8];
            blv[ni] = *(const f16x8*)&sBl[br * 40 + lq * 8];
        }
#pragma unroll
        for (int mi = 0; mi < 2; ++mi)
#pragma unroll
            for (int ni = 0; ni < 4; ++ni) {
                acc[mi][ni] = __builtin_amdgcn_mfma_f32_16x16x32_f16(ah[mi], bhv[ni], acc[mi][ni], 0, 0, 0);
                acc[mi][ni] = __builtin_amdgcn_mfma_f32_16x16x32_f16(ah[mi], blv[ni], acc[mi][ni], 0, 0, 0);
                acc[mi][ni] = __builtin_amdgcn_mfma_f32_16x16x32_f16(al[mi], bhv[ni], acc[mi][ni], 0, 0, 0);
            }
    }

    // epilogue: bias + ReLU, fp32 NHWC store
    const size_t pixbase = (size_t)bx * 64;
#pragma unroll
    for (int ni = 0; ni < 4; ++ni) {
        const int co = coy * 128 + wn * 64 + ni * 16 + l15;
        const float bv = bias[co];
#pragma unroll
        for (int mi = 0; mi < 2; ++mi) {
#pragma unroll
            for (int r = 0; r < 4; ++r) {
                const int pxl = wm * 32 + mi * 16 + lq * 4 + r;
                out[(pixbase + pxl) * COUTF + co] = fmaxf(acc[mi][ni][r] + bv, 0.f);
            }
        }
    }
}

extern "C" void kernel_launch(void* const* d_in, const int* in_sizes, int n_in,
                              void* d_out, int out_size, void* d_ws, size_t ws_size,
                              hipStream_t stream) {
    (void)in_sizes; (void)n_in; (void)out_size; (void)ws_size;
    const float* x = (const float*)d_in[0];
    const float* offs[8];
    const float* wsrc[8];
    const float* bs[8];
    for (int i = 0; i < 8; ++i) {
        offs[i] = (const float*)d_in[1 + i];
        wsrc[i] = (const float*)d_in[9 + 2 * i];
        bs[i] = (const float*)d_in[10 + 2 * i];
    }
    // workspace: bufA 32MB | bufB 16MB | wt (fp16 hi/lo) 5.25MB
    float* bufA = (float*)d_ws;
    float* bufB = (float*)((char*)d_ws + 33554432u);
    _Float16* wt = (_Float16*)((char*)d_ws + 50331648u);
    // per-layer offsets into wt, in halves
    const size_t wo[8] = {0, 262144, 851968, 1146880, 1441792, 1736704, 2031616, 2326528};
    const int cins[8] = {512, 256, 128, 128, 128, 128, 128, 128};
    const int couts[8] = {256, 128, 128, 128, 128, 128, 128, 128};
    const int kks[8] = {1, 9, 9, 9, 9, 9, 9, 9};

    nchw2nhwc<<<dim3((512 / 32) * 2, 64, 4), 256, 0, stream>>>(x, bufA, 512);
    for (int i = 0; i < 8; ++i) {
        const int total = kks[i] * cins[i] * couts[i];
        prep_w<<<(total + 255) / 256, 256, 0, stream>>>(wsrc[i], wt + wo[i],
                                                        cins[i], couts[i], kks[i], total);
    }
    dconv_mfma<1, 512, 256><<<dim3(256, 2), 256, 0, stream>>>(bufA, offs[0], wt + wo[0], bs[0], bufB);
    dconv_mfma<9, 256, 128><<<dim3(256, 1), 256, 0, stream>>>(bufB, offs[1], wt + wo[1], bs[1], bufA);
    dconv_mfma<9, 128, 128><<<dim3(256, 1), 256, 0, stream>>>(bufA, offs[2], wt + wo[2], bs[2], bufB);
    dconv_mfma<9, 128, 128><<<dim3(256, 1), 256, 0, stream>>>(bufB, offs[3], wt + wo[3], bs[3], bufA);
    dconv_mfma<9, 128, 128><<<dim3(256, 1), 256, 0, stream>>>(bufA, offs[4], wt + wo[4], bs[4], bufB);
    dconv_mfma<9, 128, 128><<<dim3(256, 1), 256, 0, stream>>>(bufB, offs[5], wt + wo[5], bs[5], bufA);
    dconv_mfma<9, 128, 128><<<dim3(256, 1), 256, 0, stream>>>(bufA, offs[6], wt + wo[6], bs[6], bufB);
    dconv_mfma<9, 128, 128><<<dim3(256, 1), 256, 0, stream>>>(bufB, offs[7], wt + wo[7], bs[7], bufA);
    nhwc2nchw<<<dim3((128 / 32) * 2, 64, 4), 256, 0, stream>>>(bufA, (float*)d_out, 128);
}

// Round 7
// 508.754 us; speedup vs baseline: 2.1240x; 1.0114x over previous
//
#include <hip/hip_runtime.h>

typedef _Float16 f16x8 __attribute__((ext_vector_type(8)));
typedef _Float16 f16x4 __attribute__((ext_vector_type(4)));
typedef float f32x4 __attribute__((ext_vector_type(4)));

// ---------------------------------------------------------------------------
// DeformConv stack: 8 layers, N=4, H=W=64.
// L0 (512->256, k=1), L1 (256->128, 3x3), L2..L7 (128->128, 3x3)
// Round-6 core (bit-exact-proven) widened from 4 waves to 8 waves (512 thr):
//   - same 64px x 128co block tile, same LDS layout (stride-40 rows),
//     same two-barrier staging, same fp16 hi/lo-split 3-term MFMA
//   - wave tile now 32px x 32co (12 MFMAs/it), acc[2][2]
//   - A-staging: 4 ch/thread; B-staging: 16B/thread
// Per-accumulator MFMA chains identical to round 6 -> output must be
// bit-exact (absmax 0.009765625). Occupancy 1 -> 2 waves/SIMD.
// ---------------------------------------------------------------------------

__global__ __launch_bounds__(256) void nchw2nhwc(const float* __restrict__ in,
                                                 float* __restrict__ out, int C) {
    const int ctiles = C >> 5;
    const int ct = blockIdx.x % ctiles;
    const int xt = blockIdx.x / ctiles;
    const int y = blockIdx.y, n = blockIdx.z;
    const int c0 = ct * 32, x0 = xt * 32;
    __shared__ float tile[32][33];
    const int tx = threadIdx.x & 31, tr = threadIdx.x >> 5;
#pragma unroll
    for (int r = 0; r < 32; r += 8) {
        const int c = c0 + tr + r;
        tile[tr + r][tx] = in[(((n * C + c) << 6) + y) * 64 + x0 + tx]; // tile[c][x]
    }
    __syncthreads();
#pragma unroll
    for (int r = 0; r < 32; r += 8) {
        const int x = x0 + tr + r;
        out[((((n << 6) + y) * 64) + x) * C + c0 + tx] = tile[tx][tr + r];
    }
}

__global__ __launch_bounds__(256) void nhwc2nchw(const float* __restrict__ in,
                                                 float* __restrict__ out, int C) {
    const int ctiles = C >> 5;
    const int ct = blockIdx.x % ctiles;
    const int xt = blockIdx.x / ctiles;
    const int y = blockIdx.y, n = blockIdx.z;
    const int c0 = ct * 32, x0 = xt * 32;
    __shared__ float tile[32][33];
    const int tx = threadIdx.x & 31, tr = threadIdx.x >> 5;
#pragma unroll
    for (int r = 0; r < 32; r += 8) {
        const int x = x0 + tr + r;
        tile[tr + r][tx] = in[((((n << 6) + y) * 64) + x) * C + c0 + tx]; // tile[x][c]
    }
    __syncthreads();
#pragma unroll
    for (int r = 0; r < 32; r += 8) {
        const int c = c0 + tr + r;
        out[(((n * C + c) << 6) + y) * 64 + x0 + tx] = tile[tx][tr + r];
    }
}

// w[cout][cin][kh][kw] fp32 -> wt rows of 64 halves: [k][chunk][co][ hi(32) | lo(32) ]
__global__ __launch_bounds__(256) void prep_w(const float* __restrict__ w,
                                              _Float16* __restrict__ wt,
                                              int CIN, int COUT, int KK, int total) {
    const int idx = blockIdx.x * 256 + threadIdx.x;
    if (idx >= total) return;
    const int e = idx & 31;
    int r = idx >> 5;
    const int co = r % COUT;
    r /= COUT;
    const int nc = CIN >> 5;
    const int c = r % nc;
    const int k = r / nc;
    const int ci = c * 32 + e;
    const float v = w[(co * CIN + ci) * KK + k];
    const _Float16 h = (_Float16)v;
    const _Float16 l = (_Float16)(v - (float)h);
    const size_t row = ((size_t)(k * nc + c) * COUT + co) * 64;
    wt[row + e] = h;
    wt[row + 32 + e] = l;
}

// Deformable conv layer. grid: (256, COUTF/128), block 512 (8 waves).
// Block tile: 64 px (one image row) x 128 couts. Wave: 32 px x 32 co.
template <int TAPS, int CIN, int COUTF>
__global__ __launch_bounds__(512) void dconv_mfma(const float* __restrict__ in,
                                                  const float* __restrict__ off,
                                                  const _Float16* __restrict__ wt,
                                                  const float* __restrict__ bias,
                                                  float* __restrict__ out) {
    constexpr int KS = (TAPS == 9) ? 3 : 1;
    constexpr int PAD = (TAPS == 9) ? 1 : 0;
    constexpr int NC = CIN / 32;          // 32-channel chunks
    constexpr int TOTAL_IT = TAPS * NC;

    // padded tiles: stride 40 halves (80 B)
    __shared__ __align__(16) _Float16 sAh[64 * 40];
    __shared__ __align__(16) _Float16 sAl[64 * 40];
    __shared__ __align__(16) _Float16 sBh[128 * 40];
    __shared__ __align__(16) _Float16 sBl[128 * 40];

    const int t = threadIdx.x;
    const int bx0 = blockIdx.x;
    const int bx = (bx0 & 7) * 32 + (bx0 >> 3); // bijective XCD swizzle (256=8*32)
    const int coy = blockIdx.y;    // 128-co tile
    const int n = bx >> 6, y = bx & 63;

    // staging roles
    const int px = t & 63;         // x coordinate / A row
    const int cg = t >> 6;         // 4-ci group (0..7) within chunk
    const int bco = t >> 2;        // B row 0..127
    const int bq = t & 3;          // 16B quarter of B row half

    // mfma roles
    const int lane = t & 63, wv = t >> 6;
    const int wm = wv & 1, wn = wv >> 1;   // wm: px half, wn: co quarter
    const int l15 = lane & 15, lq = lane >> 4;

    // bilinear state for current tap
    float w00, w01, w10, w11;
    const float *p00, *p01, *p10, *p11;

    auto mkcoef = [&](int k, float dy, float dx) {
        const int kh = k / KS, kw = k - kh * KS;
        const float py = (float)(y + kh - PAD) + dy;
        const float pxc = (float)(px + kw - PAD) + dx;
        const float y0f = floorf(py), x0f = floorf(pxc);
        const int iy0 = (int)y0f, ix0 = (int)x0f;
        const int iy1 = iy0 + 1, ix1 = ix0 + 1;
        const float wy1 = py - y0f, wy0 = 1.f - wy1;
        const float wx1 = pxc - x0f, wx0 = 1.f - wx1;
        const bool vy0 = (iy0 >= 0) & (iy0 < 64), vy1 = (iy1 >= 0) & (iy1 < 64);
        const bool vx0 = (ix0 >= 0) & (ix0 < 64), vx1 = (ix1 >= 0) & (ix1 < 64);
        w00 = (vy0 & vx0) ? wy0 * wx0 : 0.f;
        w01 = (vy0 & vx1) ? wy0 * wx1 : 0.f;
        w10 = (vy1 & vx0) ? wy1 * wx0 : 0.f;
        w11 = (vy1 & vx1) ? wy1 * wx1 : 0.f;
        const int cy0 = min(max(iy0, 0), 63), cy1 = min(max(iy1, 0), 63);
        const int cx0 = min(max(ix0, 0), 63), cx1 = min(max(ix1, 0), 63);
        p00 = in + (size_t)(((n << 6) + cy0) * 64 + cx0) * CIN + cg * 4;
        p01 = in + (size_t)(((n << 6) + cy0) * 64 + cx1) * CIN + cg * 4;
        p10 = in + (size_t)(((n << 6) + cy1) * 64 + cx0) * CIN + cg * 4;
        p11 = in + (size_t)(((n << 6) + cy1) * 64 + cx1) * CIN + cg * 4;
    };

    auto oidx = [&](int k) { return ((n * 2 * TAPS + 2 * k) * 64 + y) * 64 + px; };

    // prefetch registers (next chunk)
    float4 A00, A10, A20, A30;
    uint4 B0, B2;

    auto load_chunk = [&](int k, int c) {
        A00 = *(const float4*)(p00 + c * 32);
        A10 = *(const float4*)(p01 + c * 32);
        A20 = *(const float4*)(p10 + c * 32);
        A30 = *(const float4*)(p11 + c * 32);
        const size_t brow = ((size_t)(k * NC + c) * COUTF + coy * 128 + bco) * 64;
        const uint4* bp = (const uint4*)(wt + brow);
        B0 = bp[bq];       // 16B of hi half-row
        B2 = bp[4 + bq];   // 16B of lo half-row
    };

    auto write_chunk = [&]() {
        float v[4];
        v[0] = w00 * A00.x + w01 * A10.x + w10 * A20.x + w11 * A30.x;
        v[1] = w00 * A00.y + w01 * A10.y + w10 * A20.y + w11 * A30.y;
        v[2] = w00 * A00.z + w01 * A10.z + w10 * A20.z + w11 * A30.z;
        v[3] = w00 * A00.w + w01 * A10.w + w10 * A20.w + w11 * A30.w;
        f16x4 hv, lv;
#pragma unroll
        for (int j = 0; j < 4; ++j) {
            const _Float16 h = (_Float16)v[j];
            hv[j] = h;
            lv[j] = (_Float16)(v[j] - (float)h);
        }
        *(f16x4*)&sAh[px * 40 + cg * 4] = hv;
        *(f16x4*)&sAl[px * 40 + cg * 4] = lv;
        *(uint4*)&sBh[bco * 40 + bq * 8] = B0;
        *(uint4*)&sBl[bco * 40 + bq * 8] = B2;
    };

    // prologue
    float dyc = off[oidx(0)];
    float dxc = off[oidx(0) + 4096];
    mkcoef(0, dyc, dxc);
    float dyn = 0.f, dxn = 0.f;
    if (TAPS > 1) { dyn = off[oidx(1)]; dxn = off[oidx(1) + 4096]; }
    load_chunk(0, 0);

    f32x4 acc[2][2] = {};

    int k = 0, c = 0;
    for (int it = 0; it < TOTAL_IT; ++it) {
        __syncthreads();              // previous MFMA done reading LDS
        write_chunk();                // stage current chunk (regs -> LDS)
        if (it + 1 < TOTAL_IT) {
            int c2 = c + 1, k2 = k;
            if (c2 == NC) {
                c2 = 0; k2 = k + 1;
                mkcoef(k2, dyn, dxn);
                if (k2 + 1 < TAPS) { dyn = off[oidx(k2 + 1)]; dxn = off[oidx(k2 + 1) + 4096]; }
            }
            load_chunk(k2, c2);       // issue next-chunk loads BEFORE MFMA
            k = k2; c = c2;
        }
        __syncthreads();              // staged data visible

        f16x8 ah[2], al[2], bhv[2], blv[2];
#pragma unroll
        for (int mi = 0; mi < 2; ++mi) {
            const int ar = wm * 32 + mi * 16 + l15;
            ah[mi] = *(const f16x8*)&sAh[ar * 40 + lq * 8];
            al[mi] = *(const f16x8*)&sAl[ar * 40 + lq * 8];
        }
#pragma unroll
        for (int ni = 0; ni < 2; ++ni) {
            const int br = wn * 32 + ni * 16 + l15;
            bhv[ni] = *(const f16x8*)&sBh[br * 40 + lq * 8];
            blv[ni] = *(const f16x8*)&sBl[br * 40 + lq * 8];
        }
#pragma unroll
        for (int mi = 0; mi < 2; ++mi)
#pragma unroll
            for (int ni = 0; ni < 2; ++ni) {
                acc[mi][ni] = __builtin_amdgcn_mfma_f32_16x16x32_f16(ah[mi], bhv[ni], acc[mi][ni], 0, 0, 0);
                acc[mi][ni] = __builtin_amdgcn_mfma_f32_16x16x32_f16(ah[mi], blv[ni], acc[mi][ni], 0, 0, 0);
                acc[mi][ni] = __builtin_amdgcn_mfma_f32_16x16x32_f16(al[mi], bhv[ni], acc[mi][ni], 0, 0, 0);
            }
    }

    // epilogue: bias + ReLU, fp32 NHWC store
    const size_t pixbase = (size_t)bx * 64;
#pragma unroll
    for (int ni = 0; ni < 2; ++ni) {
        const int co = coy * 128 + wn * 32 + ni * 16 + l15;
        const float bv = bias[co];
#pragma unroll
        for (int mi = 0; mi < 2; ++mi) {
#pragma unroll
            for (int r = 0; r < 4; ++r) {
                const int pxl = wm * 32 + mi * 16 + lq * 4 + r;
                out[(pixbase + pxl) * COUTF + co] = fmaxf(acc[mi][ni][r] + bv, 0.f);
            }
        }
    }
}

extern "C" void kernel_launch(void* const* d_in, const int* in_sizes, int n_in,
                              void* d_out, int out_size, void* d_ws, size_t ws_size,
                              hipStream_t stream) {
    (void)in_sizes; (void)n_in; (void)out_size; (void)ws_size;
    const float* x = (const float*)d_in[0];
    const float* offs[8];
    const float* wsrc[8];
    const float* bs[8];
    for (int i = 0; i < 8; ++i) {
        offs[i] = (const float*)d_in[1 + i];
        wsrc[i] = (const float*)d_in[9 + 2 * i];
        bs[i] = (const float*)d_in[10 + 2 * i];
    }
    // workspace: bufA 32MB | bufB 16MB | wt (fp16 hi/lo) 5.25MB
    float* bufA = (float*)d_ws;
    float* bufB = (float*)((char*)d_ws + 33554432u);
    _Float16* wt = (_Float16*)((char*)d_ws + 50331648u);
    // per-layer offsets into wt, in halves
    const size_t wo[8] = {0, 262144, 851968, 1146880, 1441792, 1736704, 2031616, 2326528};
    const int cins[8] = {512, 256, 128, 128, 128, 128, 128, 128};
    const int couts[8] = {256, 128, 128, 128, 128, 128, 128, 128};
    const int kks[8] = {1, 9, 9, 9, 9, 9, 9, 9};

    nchw2nhwc<<<dim3((512 / 32) * 2, 64, 4), 256, 0, stream>>>(x, bufA, 512);
    for (int i = 0; i < 8; ++i) {
        const int total = kks[i] * cins[i] * couts[i];
        prep_w<<<(total + 255) / 256, 256, 0, stream>>>(wsrc[i], wt + wo[i],
                                                        cins[i], couts[i], kks[i], total);
    }
    dconv_mfma<1, 512, 256><<<dim3(256, 2), 512, 0, stream>>>(bufA, offs[0], wt + wo[0], bs[0], bufB);
    dconv_mfma<9, 256, 128><<<dim3(256, 1), 512, 0, stream>>>(bufB, offs[1], wt + wo[1], bs[1], bufA);
    dconv_mfma<9, 128, 128><<<dim3(256, 1), 512, 0, stream>>>(bufA, offs[2], wt + wo[2], bs[2], bufB);
    dconv_mfma<9, 128, 128><<<dim3(256, 1), 512, 0, stream>>>(bufB, offs[3], wt + wo[3], bs[3], bufA);
    dconv_mfma<9, 128, 128><<<dim3(256, 1), 512, 0, stream>>>(bufA, offs[4], wt + wo[4], bs[4], bufB);
    dconv_mfma<9, 128, 128><<<dim3(256, 1), 512, 0, stream>>>(bufB, offs[5], wt + wo[5], bs[5], bufA);
    dconv_mfma<9, 128, 128><<<dim3(256, 1), 512, 0, stream>>>(bufA, offs[6], wt + wo[6], bs[6], bufB);
    dconv_mfma<9, 128, 128><<<dim3(256, 1), 512, 0, stream>>>(bufB, offs[7], wt + wo[7], bs[7], bufA);
    nhwc2nchw<<<dim3((128 / 32) * 2, 64, 4), 256, 0, stream>>>(bufA, (float*)d_out, 128);
}